// Round 2
// 154.179 us; speedup vs baseline: 1.2227x; 1.2227x over previous
//
#include <hip/hip_runtime.h>
#include <math.h>

#define SB 8
#define SS 2048
#define SH 768
#define ALPHA 0.5f

typedef __fp16 f16x8 __attribute__((ext_vector_type(8)));
typedef float f32x4 __attribute__((ext_vector_type(4)));

__device__ __forceinline__ float dot4(float4 a, float4 b) {
  return a.x*b.x + a.y*b.y + a.z*b.z + a.w*b.w;
}
__device__ __forceinline__ unsigned int pk2(float a, float b) {
  return __builtin_bit_cast(unsigned int, __builtin_amdgcn_cvt_pkrtz(a, b));
}
__device__ __forceinline__ void gl_lds16(const void* g, void* l) {
  __builtin_amdgcn_global_load_lds(
      (__attribute__((address_space(1))) void*)g,
      (__attribute__((address_space(3))) void*)l, 16, 0, 0);
}

// ======================= NEW PATH (needs ~25 MB ws) =======================
// ws layout: Khs [SB*SS*SH] f16 | ksum [SB*SH] f32 | Nk[8] qsum[8] acc[8] cnt[8]

#define TI4 64                 // q-rows per band block (4 waves x 16 rows)
#define NCH4 4                 // k-tiles of 32 rows covering [i0-32, i0+96)
#define TILE_H (32 * SH)       // halves per K tile
#define TILE_B (TILE_H * 2)    // 49152 bytes per tile

// K prep: per-row norm -> Khs (f16, km/||k|| baked in), ksum = sum of rows,
// Nk = sum(km), qsum = sum(qm).  grid (64, SB), block 256 = 4 waves x 8 rows.
__global__ __launch_bounds__(256) void kprep_kernel(
    const float* __restrict__ K, const float* __restrict__ km,
    const float* __restrict__ qm,
    __fp16* __restrict__ Khs, float* __restrict__ ksum,
    float* __restrict__ Nk, float* __restrict__ qsum) {
  __shared__ float4 red[4][3][64];     // 12 KB
  int b = blockIdx.y, jc = blockIdx.x, t = threadIdx.x;
  int w = t >> 6, lane = t & 63;
  int j0 = jc * 32;
  float4 acc0 = {0,0,0,0}, acc1 = {0,0,0,0}, acc2 = {0,0,0,0};
  for (int jj = 0; jj < 8; ++jj) {
    int j = j0 + 8 * w + jj;
    const float4* rp = (const float4*)(K + ((size_t)b * SS + j) * SH);
    float4 a = rp[lane], b4 = rp[lane + 64], c4 = rp[lane + 128];
    float ssv = dot4(a, a) + dot4(b4, b4) + dot4(c4, c4);
    #pragma unroll
    for (int m = 1; m < 64; m <<= 1) ssv += __shfl_xor(ssv, m, 64);
    float kwj = km[b * SS + j] / fmaxf(sqrtf(ssv), 1e-12f);
    uint2* kr = (uint2*)(Khs + ((size_t)b * SS + j) * SH);
    kr[lane]       = make_uint2(pk2(a.x*kwj,  a.y*kwj),  pk2(a.z*kwj,  a.w*kwj));
    kr[lane + 64]  = make_uint2(pk2(b4.x*kwj, b4.y*kwj), pk2(b4.z*kwj, b4.w*kwj));
    kr[lane + 128] = make_uint2(pk2(c4.x*kwj, c4.y*kwj), pk2(c4.z*kwj, c4.w*kwj));
    acc0.x += a.x*kwj;  acc0.y += a.y*kwj;  acc0.z += a.z*kwj;  acc0.w += a.w*kwj;
    acc1.x += b4.x*kwj; acc1.y += b4.y*kwj; acc1.z += b4.z*kwj; acc1.w += b4.w*kwj;
    acc2.x += c4.x*kwj; acc2.y += c4.y*kwj; acc2.z += c4.z*kwj; acc2.w += c4.w*kwj;
  }
  red[w][0][lane] = acc0; red[w][1][lane] = acc1; red[w][2][lane] = acc2;
  __syncthreads();
  if (t < 192) {
    int s = t >> 6, l = t & 63;
    float4 r0 = red[0][s][l], r1 = red[1][s][l], r2 = red[2][s][l], r3 = red[3][s][l];
    float* kp = ksum + b * SH + (s * 64 + l) * 4;
    atomicAdd(kp + 0, r0.x+r1.x+r2.x+r3.x);
    atomicAdd(kp + 1, r0.y+r1.y+r2.y+r3.y);
    atomicAdd(kp + 2, r0.z+r1.z+r2.z+r3.z);
    atomicAdd(kp + 3, r0.w+r1.w+r2.w+r3.w);
  }
  if (t < 32) {
    float pkm = km[b * SS + j0 + t];
    float pqm = qm[b * SS + j0 + t];
    #pragma unroll
    for (int m = 1; m < 32; m <<= 1) {
      pkm += __shfl_xor(pkm, m, 64);
      pqm += __shfl_xor(pqm, m, 64);
    }
    if (t == 0) { atomicAdd(&Nk[b], pkm); atomicAdd(&qsum[b], pqm); }
  }
}

// Band kernel: 64 q-rows/block, 4 waves; each wave owns 16 q-rows with full
// K=768 (A-frags in regs), computes both 16-col k-subtiles of each 32-row
// K tile. Tiles DMA'd f16 via global_load_lds (linear dest, XOR-swizzled
// source per rule #21), double-buffered, counted vmcnt.
__global__ __launch_bounds__(256, 1) void band_kernel(
    const float* __restrict__ Q, const __fp16* __restrict__ Khs,
    const float* __restrict__ temp, const float* __restrict__ qm,
    const float* __restrict__ ksum, const float* __restrict__ Nkp,
    const float* __restrict__ qsum,
    float* __restrict__ acc, int* __restrict__ cnt, float* __restrict__ out) {
  __shared__ __fp16 kh[2 * TILE_H];    // 96 KB double buffer (1 block/CU)
  __shared__ float tab_s[64];
  __shared__ float wred[4];
  int tid = threadIdx.x;
  int w = tid >> 6, lane = tid & 63;
  int l15 = lane & 15, quad = lane >> 4;
  int blk = blockIdx.x;
  int work = (blk & 7) * 32 + (blk >> 3);  // grid 256: batch b -> XCD b
  int b = work >> 5;
  int i0 = (work & 31) * TI4;

  if (tid < 64) {
    float invt = 1.0f / temp[0];
    tab_s[tid] = __expf(-ALPHA * fabsf((float)(tid - 31))) * invt;
  }

  int qrow = i0 + w * 16 + l15;
  float qmv = qm[b * SS + qrow];
  float nk = Nkp[b];

  // swizzled per-lane source offsets (tile-relative bytes), linear LDS dest.
  // LDS linear byte d holds global byte  r*1536 + ((d%1536) ^ ((r&7)<<4)).
  int srcoff[12];
  {
    int base = (w << 10) + (lane << 4);
    #pragma unroll
    for (int u = 0; u < 12; ++u) {
      int d = base + (u << 12);
      int r = d / 1536;
      int cb = d - r * 1536;
      srcoff[u] = r * 1536 + (cb ^ ((r & 7) << 4));
    }
  }

  // ---- prologue: full-row A-frags (f16), ||q||^2 and d0 = q.ksum partials
  const float* qp = Q + ((size_t)b * SS + qrow) * SH + quad * 8;
  const float* kp = ksum + (size_t)b * SH + quad * 8;
  f16x8 afr[24];
  float ss = 0.f, dd = 0.f;
  #pragma unroll
  for (int s = 0; s < 24; ++s) {
    float4 x0 = *(const float4*)(qp + 32 * s);
    float4 x1 = *(const float4*)(qp + 32 * s + 4);
    float4 k0 = *(const float4*)(kp + 32 * s);
    float4 k1 = *(const float4*)(kp + 32 * s + 4);
    ss += dot4(x0, x0) + dot4(x1, x1);
    dd += dot4(x0, k0) + dot4(x1, k1);
    uint4 u = make_uint4(pk2(x0.x, x0.y), pk2(x0.z, x0.w),
                         pk2(x1.x, x1.y), pk2(x1.z, x1.w));
    afr[s] = __builtin_bit_cast(f16x8, u);
  }

  const __fp16* KbH = Khs + (size_t)b * SS * SH;
  auto stage = [&](int c) {              // 12 x gl_lds(16B) per thread
    int jlo = i0 - 32 + 32 * c;
    int jcl = min(max(jlo, 0), SS - 32); // whole-tile clamp; masked in epilogue
    const char* src = (const char*)KbH + (size_t)jcl * (SH * 2);
    char* dst = (char*)kh + (c & 1) * TILE_B + (w << 10);   // wave-uniform base
    #pragma unroll
    for (int u = 0; u < 12; ++u)
      gl_lds16(src + srcoff[u], dst + (u << 12));
  };
  stage(0);                              // tile0 DMA overlaps reductions below

  ss += __shfl_xor(ss, 16, 64); ss += __shfl_xor(ss, 32, 64);
  dd += __shfl_xor(dd, 16, 64); dd += __shfl_xor(dd, 32, 64);
  float qw = qmv / fmaxf(sqrtf(ss), 1e-12f);
  float qwsr[4], d0r[4];
  #pragma unroll
  for (int r = 0; r < 4; ++r) {          // values for epilogue rows quad*4+r
    qwsr[r] = __shfl(qw, quad * 4 + r, 64);
    d0r[r]  = __shfl(dd, quad * 4 + r, 64);
  }

  float an[2][4] = {{0,0,0,0},{0,0,0,0}};
  float ad[2][4] = {{0,0,0,0},{0,0,0,0}};
  asm volatile("s_waitcnt lgkmcnt(0)" ::: "memory");  // tab_s visible pre-barrier

  for (int c = 0; c < NCH4; ++c) {
    if (c + 1 < NCH4) {
      stage(c + 1);                                   // 24 outstanding
      __builtin_amdgcn_sched_barrier(0);              // pin issue before wait
      asm volatile("s_waitcnt vmcnt(12)" ::: "memory"); // tile c landed, c+1 flies
    } else {
      asm volatile("s_waitcnt vmcnt(0)" ::: "memory");
    }
    __builtin_amdgcn_s_barrier();
    __builtin_amdgcn_sched_barrier(0);

    const __fp16* tb = kh + (c & 1) * TILE_H;
    int ro0 = l15 * SH, ro1 = (l15 + 16) * SH;        // halves
    int xr = (l15 & 7) << 3;                          // read-side XOR (halves)
    f32x4 d0a = {0,0,0,0}, d0b = {0,0,0,0}, d1a = {0,0,0,0}, d1b = {0,0,0,0};
    #pragma unroll
    for (int s = 0; s < 24; ++s) {
      int cc = ((quad << 3) + (s << 5)) ^ xr;
      f16x8 b0 = *(const f16x8*)(tb + ro0 + cc);
      f16x8 b1 = *(const f16x8*)(tb + ro1 + cc);
      if (s & 1) {
        d0b = __builtin_amdgcn_mfma_f32_16x16x32_f16(afr[s], b0, d0b, 0, 0, 0);
        d1b = __builtin_amdgcn_mfma_f32_16x16x32_f16(afr[s], b1, d1b, 0, 0, 0);
      } else {
        d0a = __builtin_amdgcn_mfma_f32_16x16x32_f16(afr[s], b0, d0a, 0, 0, 0);
        d1a = __builtin_amdgcn_mfma_f32_16x16x32_f16(afr[s], b1, d1a, 0, 0, 0);
      }
    }
    asm volatile("" ::: "memory");
    __builtin_amdgcn_s_barrier();        // buf reads done -> next DMA may land
    asm volatile("" ::: "memory");

    // epilogue (all lanes; regs + tab_s only -> overlaps next-tile DMA)
    int jlo = i0 - 32 + 32 * c;
    f32x4 dt0 = d0a + d0b, dt1 = d1a + d1b;
    #pragma unroll
    for (int tk = 0; tk < 2; ++tk) {
      f32x4 dt = tk ? dt1 : dt0;
      int j = jlo + tk * 16 + l15;
      float vmask = ((unsigned)j < SS) ? 1.0f : 0.0f;
      int idxbase = j - i0 - w * 16 + 31;
      #pragma unroll
      for (int reg = 0; reg < 4; ++reg) {
        float sv = dt[reg] * qwsr[reg];  // = sim (kw baked into Khs)
        int idx = min(max(idxbase - quad * 4 - reg, 0), 63);
        float ev = (__expf(sv * tab_s[idx]) - 1.0f) * vmask;
        an[tk][reg] += ev * sv;
        ad[tk][reg] += ev;
      }
    }
  }

  // fold k-cols (l15) per row, combine subtiles, score, block total
  float tot = 0.f;
  #pragma unroll
  for (int reg = 0; reg < 4; ++reg) {
    float a = an[0][reg] + an[1][reg];
    float e = ad[0][reg] + ad[1][reg];
    a += __shfl_xor(a, 1, 64); a += __shfl_xor(a, 2, 64);
    a += __shfl_xor(a, 4, 64); a += __shfl_xor(a, 8, 64);
    e += __shfl_xor(e, 1, 64); e += __shfl_xor(e, 2, 64);
    e += __shfl_xor(e, 4, 64); e += __shfl_xor(e, 8, 64);
    tot += (qwsr[reg] * d0r[reg] + a) / (nk + e);
  }
  tot += __shfl_xor(tot, 16, 64);
  tot += __shfl_xor(tot, 32, 64);
  if (lane == 0) wred[w] = tot;
  __syncthreads();
  if (tid == 0) {
    float t = wred[0] + wred[1] + wred[2] + wred[3];
    atomicAdd(&acc[b], t);
    __threadfence();
    if (atomicAdd(&cnt[b], 1) == (SS / TI4) - 1) {  // last of 32 blocks for b
      float a2 = atomicAdd(&acc[b], 0.0f);
      out[b] = a2 / fmaxf(qsum[b], 1.0f);
    }
  }
}

// ================== FALLBACK PATH (round-0 kernel, ~90 KB ws) ==================
#define TI 16
#define NCH 5
#define RSH 776

__global__ __launch_bounds__(256) void kprep0_kernel(
    const float* __restrict__ K, const float* __restrict__ km,
    const float* __restrict__ qm,
    float* __restrict__ kw, float* __restrict__ ksum,
    float* __restrict__ Nk, float* __restrict__ qsum) {
  __shared__ float4 red[4][3][64];
  int b = blockIdx.y, jc = blockIdx.x, t = threadIdx.x;
  int w = t >> 6, lane = t & 63;
  int j0 = jc * 32;
  float4 acc0 = {0,0,0,0}, acc1 = {0,0,0,0}, acc2 = {0,0,0,0};
  for (int jj = 0; jj < 8; ++jj) {
    int j = j0 + 8 * w + jj;
    const float4* rp = (const float4*)(K + ((size_t)b * SS + j) * SH);
    float4 a = rp[lane], b4 = rp[lane + 64], c4 = rp[lane + 128];
    float ssv = dot4(a, a) + dot4(b4, b4) + dot4(c4, c4);
    #pragma unroll
    for (int m = 1; m < 64; m <<= 1) ssv += __shfl_xor(ssv, m, 64);
    float kwj = km[b * SS + j] / fmaxf(sqrtf(ssv), 1e-12f);
    if (lane == 0) kw[b * SS + j] = kwj;
    acc0.x += a.x*kwj;  acc0.y += a.y*kwj;  acc0.z += a.z*kwj;  acc0.w += a.w*kwj;
    acc1.x += b4.x*kwj; acc1.y += b4.y*kwj; acc1.z += b4.z*kwj; acc1.w += b4.w*kwj;
    acc2.x += c4.x*kwj; acc2.y += c4.y*kwj; acc2.z += c4.z*kwj; acc2.w += c4.w*kwj;
  }
  red[w][0][lane] = acc0; red[w][1][lane] = acc1; red[w][2][lane] = acc2;
  __syncthreads();
  if (t < 192) {
    int s = t >> 6, l = t & 63;
    float4 r0 = red[0][s][l], r1 = red[1][s][l], r2 = red[2][s][l], r3 = red[3][s][l];
    float* kp = ksum + b * SH + (s * 64 + l) * 4;
    atomicAdd(kp + 0, r0.x+r1.x+r2.x+r3.x);
    atomicAdd(kp + 1, r0.y+r1.y+r2.y+r3.y);
    atomicAdd(kp + 2, r0.z+r1.z+r2.z+r3.z);
    atomicAdd(kp + 3, r0.w+r1.w+r2.w+r3.w);
  }
  if (t < 32) {
    float pkm = km[b * SS + j0 + t];
    float pqm = qm[b * SS + j0 + t];
    #pragma unroll
    for (int m = 1; m < 32; m <<= 1) {
      pkm += __shfl_xor(pkm, m, 64);
      pqm += __shfl_xor(pqm, m, 64);
    }
    if (t == 0) { atomicAdd(&Nk[b], pkm); atomicAdd(&qsum[b], pqm); }
  }
}

__global__ __launch_bounds__(256, 4) void band0_kernel(
    const float* __restrict__ Q, const float* __restrict__ K,
    const float* __restrict__ temp, const float* __restrict__ qm,
    const float* __restrict__ kw,
    const float* __restrict__ ksum, const float* __restrict__ Nkp,
    const float* __restrict__ qsum,
    float* __restrict__ acc, int* __restrict__ cnt, float* __restrict__ out) {
  __shared__ __fp16 kh[TI * RSH];
  __shared__ float sC[1024];
  __shared__ float tab_s[64];
  __shared__ float qws[TI], d0s[TI], kwc[TI];
  int tid = threadIdx.x;
  int w = tid >> 6, lane = tid & 63;
  int l15 = lane & 15, quad = lane >> 4;
  int blk = blockIdx.x;
  int work = (blk & 7) * 128 + (blk >> 3);
  int b = work >> 7;
  int i0 = (work & 127) * TI;
  if (tid < 64) {
    float invt = 1.0f / temp[0];
    tab_s[tid] = __expf(-ALPHA * fabsf((float)(tid - 31))) * invt;
  }
  f16x8 afr[6];
  {
    const float* qrow = Q + (size_t)(b * SS + i0 + l15) * SH + w * 192 + quad * 8;
    const float* ksb  = ksum + (size_t)b * SH + w * 192 + quad * 8;
    float ssp = 0.f, d0p = 0.f;
    #pragma unroll
    for (int s = 0; s < 6; ++s) {
      float4 x0 = *(const float4*)(qrow + 32 * s);
      float4 x1 = *(const float4*)(qrow + 32 * s + 4);
      float4 k0 = *(const float4*)(ksb + 32 * s);
      float4 k1 = *(const float4*)(ksb + 32 * s + 4);
      ssp += dot4(x0, x0) + dot4(x1, x1);
      d0p += dot4(x0, k0) + dot4(x1, k1);
      uint4 u = make_uint4(pk2(x0.x,x0.y), pk2(x0.z,x0.w),
                           pk2(x1.x,x1.y), pk2(x1.z,x1.w));
      afr[s] = __builtin_bit_cast(f16x8, u);
    }
    sC[(w * 64 + lane) * 2]     = ssp;
    sC[(w * 64 + lane) * 2 + 1] = d0p;
  }
  __syncthreads();
  if (tid < TI) {
    float ssl = 0.f, ddl = 0.f;
    #pragma unroll
    for (int p = 0; p < 16; ++p) {
      int idx = ((p >> 2) * 64 + (p & 3) * 16 + tid) * 2;
      ssl += sC[idx]; ddl += sC[idx + 1];
    }
    qws[tid] = qm[b * SS + i0 + tid] / fmaxf(sqrtf(ssl), 1e-12f);
    d0s[tid] = ddl;
  }
  float nk = Nkp[b];
  const float* Kb = K + (size_t)b * SS * SH;
  const float* kwb = kw + b * SS;

  int prow = tid >> 4, pseg = tid & 15;
  float4 pf[12];
  {
    int jcl = min(max(i0 - 32 + prow, 0), SS - 1);
    const float4* src = (const float4*)(Kb + (size_t)jcl * SH + pseg * 48);
    #pragma unroll
    for (int u = 0; u < 12; ++u) pf[u] = src[u];
  }

  float anv[4] = {0,0,0,0}, adv[4] = {0,0,0,0};
  for (int c = 0; c < NCH; ++c) {
    int jlo = i0 - 32 + 16 * c;
    __syncthreads();
    {
      uint4* dst = (uint4*)(kh + prow * RSH + pseg * 48);
      #pragma unroll
      for (int u = 0; u < 6; ++u) {
        float4 a = pf[2*u], bb = pf[2*u+1];
        dst[u] = make_uint4(pk2(a.x,a.y), pk2(a.z,a.w), pk2(bb.x,bb.y), pk2(bb.z,bb.w));
      }
      if (tid < TI) {
        int j = jlo + tid;
        kwc[tid] = (j >= 0 && j < SS) ? kwb[j] : 0.0f;
      }
    }
    __syncthreads();
    if (c + 1 < NCH) {
      int jcl = min(max(jlo + 16 + prow, 0), SS - 1);
      const float4* src = (const float4*)(Kb + (size_t)jcl * SH + pseg * 48);
      #pragma unroll
      for (int u = 0; u < 12; ++u) pf[u] = src[u];
    }
    f32x4 d = {0.f, 0.f, 0.f, 0.f};
    {
      const __fp16* bbase = kh + l15 * RSH + w * 192 + quad * 8;
      #pragma unroll
      for (int s = 0; s < 6; ++s) {
        f16x8 bf = *(const f16x8*)(bbase + 32 * s);
        d = __builtin_amdgcn_mfma_f32_16x16x32_f16(afr[s], bf, d, 0, 0, 0);
      }
    }
    {
      float4* cw = (float4*)sC;
      cw[w * 64 + lane] = make_float4(d[0], d[1], d[2], d[3]);
    }
    __syncthreads();
    if (w == 0) {
      const float4* cr = (const float4*)sC;
      float4 t0 = cr[lane], t1 = cr[64 + lane], t2 = cr[128 + lane], t3 = cr[192 + lane];
      float sx[4] = {t0.x+t1.x+t2.x+t3.x, t0.y+t1.y+t2.y+t3.y,
                     t0.z+t1.z+t2.z+t3.z, t0.w+t1.w+t2.w+t3.w};
      int base = jlo - i0 + 31 + l15;
      float kwv = kwc[l15];
      #pragma unroll
      for (int reg = 0; reg < 4; ++reg) {
        int rowl = quad * 4 + reg;
        float sv = sx[reg] * qws[rowl] * kwv;
        int idx = min(max(base - rowl, 0), 63);
        float ev = __expf(sv * tab_s[idx]) - 1.0f;
        anv[reg] += ev * sv;
        adv[reg] += ev;
      }
    }
  }

  if (w == 0) {
    float tot = 0.f;
    #pragma unroll
    for (int reg = 0; reg < 4; ++reg) {
      float a = anv[reg], e = adv[reg];
      a += __shfl_xor(a, 1, 64); a += __shfl_xor(a, 2, 64);
      a += __shfl_xor(a, 4, 64); a += __shfl_xor(a, 8, 64);
      e += __shfl_xor(e, 1, 64); e += __shfl_xor(e, 2, 64);
      e += __shfl_xor(e, 4, 64); e += __shfl_xor(e, 8, 64);
      int rowl = quad * 4 + reg;
      tot += (qws[rowl] * d0s[rowl] + a) / (nk + e);
    }
    tot += __shfl_xor(tot, 16, 64);
    tot += __shfl_xor(tot, 32, 64);
    if (lane == 0) {
      atomicAdd(&acc[b], tot);
      __threadfence();
      if (atomicAdd(&cnt[b], 1) == 127) {
        float a = atomicAdd(&acc[b], 0.0f);
        out[b] = a / fmaxf(qsum[b], 1.0f);
      }
    }
  }
}

extern "C" void kernel_launch(void* const* d_in, const int* in_sizes, int n_in,
                              void* d_out, int out_size, void* d_ws, size_t ws_size,
                              hipStream_t stream) {
  const float* Q    = (const float*)d_in[0];
  const float* K    = (const float*)d_in[1];
  const float* qm   = (const float*)d_in[2];
  const float* km   = (const float*)d_in[3];
  const float* temp = (const float*)d_in[4];
  float* outp = (float*)d_out;

  const size_t KHS_BYTES = (size_t)SB * SS * SH * 2;  // ~24 MB
  const size_t NEED = KHS_BYTES + (size_t)(SB * SH + 32) * sizeof(float);

  if (ws_size >= NEED) {
    // -------- new path --------
    __fp16* Khs = (__fp16*)d_ws;
    float* ksum = (float*)((char*)d_ws + KHS_BYTES);
    float* Nk   = ksum + SB * SH;
    float* qsum = Nk + 8;
    float* accb = qsum + 8;
    int*   cnt  = (int*)(accb + 8);
    (void)hipMemsetAsync(ksum, 0, (SB * SH + 32) * sizeof(float), stream);
    kprep_kernel<<<dim3(64, SB), 256, 0, stream>>>(K, km, qm, Khs, ksum, Nk, qsum);
    band_kernel<<<SB * (SS / TI4), 256, 0, stream>>>(Q, Khs, temp, qm, ksum, Nk,
                                                     qsum, accb, cnt, outp);
  } else {
    // -------- fallback: round-0 kernel (ws ~90 KB) --------
    float* ws   = (float*)d_ws;
    float* kw   = ws;
    float* ksum = ws + SB * SS;
    float* Nk   = ksum + SB * SH;
    float* qsum = Nk + 8;
    float* accb = qsum + 8;
    int*   cnt  = (int*)(accb + 8);
    (void)hipMemsetAsync(ksum, 0, (SB * SH + 32) * sizeof(float), stream);
    kprep0_kernel<<<dim3(64, SB), 256, 0, stream>>>(K, km, qm, kw, ksum, Nk, qsum);
    band0_kernel<<<SB * (SS / TI), 256, 0, stream>>>(Q, K, temp, qm, kw, ksum, Nk,
                                                     qsum, accb, cnt, outp);
  }
}